// Round 4
// baseline (4065.123 us; speedup 1.0000x reference)
//
#include <hip/hip_runtime.h>
#include <hip/hip_bf16.h>

// GRU (B=512,T=128,I=128,H=768) + FC(768->256 relu ->10), fp32 in/out.
// Round 4: PERSISTENT kernel — 1 cooperative dispatch runs all 128 timesteps
// (kills ~10us/dispatch x128 launch overhead). W resident in LDS (126 KB,
// loaded once); per-step staging = A (h hi/lo, x) only, 2-buffer vmcnt(0)
// pipeline. Inter-block per-bg barrier: agent-scope atomics + release/acquire
// fences (wbl2/inv) for cross-XCD h visibility. 2-pass split precision.

typedef unsigned short u16;
typedef float    f32x4    __attribute__((ext_vector_type(4)));
typedef unsigned uint32x4 __attribute__((ext_vector_type(4)));
typedef __bf16   bf16x8   __attribute__((ext_vector_type(8)));

#define MFMA16 __builtin_amdgcn_mfma_f32_16x16x32_bf16

#define GLOAD16(gp, lp)                                                        \
  __builtin_amdgcn_global_load_lds(                                            \
      (const __attribute__((address_space(1))) void*)(gp),                     \
      (__attribute__((address_space(3))) void*)(lp), 16, 0, 0)

__device__ __forceinline__ float bf2f(u16 u) {
  unsigned v = ((unsigned)u) << 16;
  return __builtin_bit_cast(float, v);
}
__device__ __forceinline__ u16 f2bf(float f) {  // round-to-nearest-even
  unsigned x = __builtin_bit_cast(unsigned, f);
  unsigned r = (x + 0x7fffu + ((x >> 16) & 1u)) >> 16;
  return (u16)r;
}
__device__ __forceinline__ float sigm(float x) {
  x = fminf(fmaxf(x, -30.f), 30.f);
  return 1.f / (1.f + __expf(-x));
}
__device__ __forceinline__ float tanhx(float x) {
  x = fminf(fmaxf(x, -15.f), 15.f);
  float ex = __expf(2.f * x);
  return (ex - 1.f) / (ex + 1.f);
}

// ---------------- prep: pack + swizzle weights (hi bf16, 72 rows/body) -----
// Wg[jb 0..31][bt 0..13][r 0..71][c8 0..7][e 0..7] u16; r = g*24 + c (c<24).
// slot c8 holds kc = c8 ^ (r&7); k = bt*64 + kc*8 + e.
// k<768 -> w_hh[g*768+jb*24+c][k], else w_ih[...][k-768].
__global__ __launch_bounds__(256) void k_prep_w(
    const float* __restrict__ w_ih, const float* __restrict__ w_hh,
    u16* __restrict__ Wg) {
  int idx = blockIdx.x * 256 + threadIdx.x;     // < 32*14*72*64 = 2064384
  int e = idx & 7, c8 = (idx >> 3) & 7;
  int r3 = idx >> 6;
  int r = r3 % 72;
  int jbt = r3 / 72;
  int bt = jbt % 14, jb = jbt / 14;
  int kc = c8 ^ (r & 7);
  int k = bt * 64 + kc * 8 + e;
  int g = r / 24, c = r % 24;
  int grow = g * 768 + jb * 24 + c;
  float v = (k < 768) ? w_hh[grow * 768 + k] : w_ih[grow * 128 + (k - 768)];
  Wg[idx] = f2bf(v);
}

// xpk[t][bt' 0..1][row 0..511][c16][e] u16 (hi/lo 16-chunk, row&15 XOR)
__global__ __launch_bounds__(256) void k_prep_x(
    const float* __restrict__ x, u16* __restrict__ xpk) {
  int idx = blockIdx.x * 256 + threadIdx.x;     // < 128*2*512*128 = 16777216
  int e = idx & 7, c16 = (idx >> 3) & 15;
  int row = (idx >> 7) & 511;
  int tb = idx >> 16;
  int bt = tb & 1, t = tb >> 1;
  int lc = c16 ^ (row & 15);
  int hl = lc >> 3, kc = lc & 7;
  int i = bt * 64 + kc * 8 + e;
  float v = x[(row * 128 + t) * 128 + i];
  u16 h = f2bf(v);
  xpk[idx] = hl ? f2bf(v - bf2f(h)) : h;
}

// w_fc1T[k][n] = w_fc1[n][k]
__global__ __launch_bounds__(256) void k_prep_fc1t(
    const float* __restrict__ w_fc1, float* __restrict__ wT) {
  int idx = blockIdx.x * 256 + threadIdx.x;     // < 768*256
  int k = idx >> 8, n = idx & 255;
  wT[idx] = w_fc1[n * 768 + k];
}

// ---------------- persistent GRU kernel (all 128 timesteps) ----------------
// grid 256 = (bg 0..7: 64 rows) x (jb 0..31: 24 h-cols); bid = bg*32+jb
// 512 thr = 8 waves: mg = wv&3 (16-row m-tile), sg = wv>>2 (16-col half/gate)
__global__ __launch_bounds__(512) void k_gru_all(
    const u16* __restrict__ Wg, const u16* __restrict__ xpk,
    u16* __restrict__ hA, u16* __restrict__ hB,
    const float* __restrict__ b_ih, const float* __restrict__ b_hh,
    unsigned* __restrict__ bar) {
  __shared__ __align__(16) u16 sW[64512];      // 126 KB: W slice, resident
  __shared__ __align__(16) u16 sA[2][8192];    // 2 x 16 KB: A double buffer
  const int tid = threadIdx.x;
  const int lane = tid & 63, wv = tid >> 6;
  const int mg = wv & 3, sg = wv >> 2;
  const int l15 = lane & 15, lg = lane >> 4;
  const int bid = blockIdx.x;
  const int jb = bid & 31, bg = bid >> 5;   // jb%8 = XCD -> W slice L2-local
  const int mbase = bg * 64;

  // ---- load W slice into LDS once (126 chunks of 1 KB) ----
  {
    const u16* wbase = Wg + (size_t)jb * 64512;
    for (int ch = wv; ch < 126; ch += 8)
      GLOAD16(wbase + ch * 512 + lane * 8, &sW[ch * 512]);
  }
  asm volatile("s_waitcnt vmcnt(0)" ::: "memory");
  __syncthreads();

  // ---- precomputed fragment offsets (u16 units) ----
  const int cc = sg * 16 + l15;
  const int ccv = (cc < 24) ? cc : (cc - 8);   // invalid lanes alias rows
  int aOff[2][2], bOff[3][2];
#pragma unroll
  for (int kk = 0; kk < 2; ++kk) {
    const int sw = (((kk << 2) + lg) ^ (l15 & 7)) << 3;
#pragma unroll
    for (int hl = 0; hl < 2; ++hl)
      aOff[kk][hl] = (mg * 16 + l15) * 128 +
                     ((((hl << 3) + (kk << 2) + lg) ^ l15) << 3);
#pragma unroll
    for (int g = 0; g < 3; ++g)
      bOff[g][kk] = (g * 24 + ccv) * 64 + sw;
  }
  const int schunk = wv * 2;                   // this wave's 2 staging chunks

  // epilogue constants
  const int j = jb * 24 + cc;                  // may be >= valid; guarded
  const bool jvalid = (cc < 24);
  float br = 0.f, bz = 0.f, bni = 0.f, bnh = 0.f;
  if (jvalid) {
    br = b_ih[j] + b_hh[j];
    bz = b_ih[768 + j] + b_hh[768 + j];
    bni = b_ih[1536 + j]; bnh = b_hh[1536 + j];
  }
  const int ebt = j >> 6, ekr = j & 63;
  const int ekc = ekr >> 3, eke = ekr & 7;
  unsigned* mybar = bar + bg * 16;             // 64B-strided counters

#pragma unroll 1
  for (int t = 0; t < 128; ++t) {
    const u16* hcur = (t & 1) ? hB : hA;
    u16* hnxt = (t & 1) ? hA : hB;
    const u16* xpt = xpk + (size_t)t * 131072;
    const u16* hsl = hcur + mbase * 128;
    const u16* xsl = xpt + mbase * 128;

    f32x4 acc0 = {0.f, 0.f, 0.f, 0.f};  // r
    f32x4 acc1 = {0.f, 0.f, 0.f, 0.f};  // z
    f32x4 acc2 = {0.f, 0.f, 0.f, 0.f};  // n (h-part)
    f32x4 acc3 = {0.f, 0.f, 0.f, 0.f};  // n (x-part)

    // prologue: stage body 0
    GLOAD16(hsl + schunk * 512 + lane * 8, &sA[0][schunk * 512]);
    GLOAD16(hsl + (schunk + 1) * 512 + lane * 8, &sA[0][(schunk + 1) * 512]);
    asm volatile("s_waitcnt vmcnt(0)" ::: "memory");
    __builtin_amdgcn_s_barrier();
    asm volatile("" ::: "memory");

#pragma unroll
    for (int bt = 0; bt < 14; ++bt) {
      const int buf = bt & 1;
      if (bt < 13) {                    // stage next body (issued early)
        const int nt = bt + 1;
        const u16* ab = (nt < 12) ? hsl + nt * 65536 : xsl + (nt - 12) * 65536;
        GLOAD16(ab + schunk * 512 + lane * 8, &sA[buf ^ 1][schunk * 512]);
        GLOAD16(ab + (schunk + 1) * 512 + lane * 8,
                &sA[buf ^ 1][(schunk + 1) * 512]);
      }
      bf16x8 Ah[2], Al[2], Bf[3][2];
#pragma unroll
      for (int kk = 0; kk < 2; ++kk) {
        Ah[kk] = *(const bf16x8*)&sA[buf][aOff[kk][0]];
        Al[kk] = *(const bf16x8*)&sA[buf][aOff[kk][1]];
#pragma unroll
        for (int g = 0; g < 3; ++g)
          Bf[g][kk] = *(const bf16x8*)&sW[bt * 4608 + bOff[g][kk]];
      }
      __builtin_amdgcn_s_setprio(1);
#pragma unroll
      for (int kk = 0; kk < 2; ++kk)
#pragma unroll
        for (int ps = 0; ps < 2; ++ps) {
          const bf16x8 Aop = ps ? Al[kk] : Ah[kk];
          acc0 = MFMA16(Aop, Bf[0][kk], acc0, 0, 0, 0);
          acc1 = MFMA16(Aop, Bf[1][kk], acc1, 0, 0, 0);
          if (bt < 12) acc2 = MFMA16(Aop, Bf[2][kk], acc2, 0, 0, 0);
          else         acc3 = MFMA16(Aop, Bf[2][kk], acc3, 0, 0, 0);
        }
      __builtin_amdgcn_s_setprio(0);
      if (bt < 13) {
        asm volatile("s_waitcnt vmcnt(0)" ::: "memory");
        __builtin_amdgcn_s_barrier();
        asm volatile("" ::: "memory");
      }
    }

    // ---- epilogue: gates + h update. C layout: col=lane&15, row=(lg)*4+e
    if (jvalid) {
#pragma unroll
      for (int e = 0; e < 4; ++e) {
        const int row = mbase + mg * 16 + lg * 4 + e;
        const int hidx = (ebt * 512 + row) * 128 + ((ekc ^ (row & 15)) << 3) + eke;
        const float hold = bf2f(hcur[hidx]) + bf2f(hcur[hidx ^ 64]);
        const float rg = sigm(acc0[e] + br);
        const float zg = sigm(acc1[e] + bz);
        const float ng = tanhx(acc3[e] + bni + rg * (acc2[e] + bnh));
        const float hv = (1.f - zg) * ng + zg * hold;
        const u16 uh = f2bf(hv);
        hnxt[hidx] = uh;
        hnxt[hidx ^ 64] = f2bf(hv - bf2f(uh));
      }
    }

    if (t == 127) break;               // final h consumed by k_fc1 after end

    // ---- inter-block step barrier (32 blocks sharing bg, cross-XCD) ----
    __syncthreads();                   // drains all waves' stores (vmcnt 0)
    if (tid == 0) {
      __builtin_amdgcn_fence(__ATOMIC_RELEASE, "agent");   // wbl2
      __hip_atomic_fetch_add(mybar, 1u, __ATOMIC_RELAXED,
                             __HIP_MEMORY_SCOPE_AGENT);
      const unsigned tgt = 32u * (unsigned)(t + 1);
      while (__hip_atomic_load(mybar, __ATOMIC_RELAXED,
                               __HIP_MEMORY_SCOPE_AGENT) < tgt)
        __builtin_amdgcn_s_sleep(2);
    }
    __syncthreads();
    __builtin_amdgcn_fence(__ATOMIC_ACQUIRE, "agent");     // inv stale L2
  }
}

// ---------------- FC tail (fp32) ----------------
__global__ __launch_bounds__(256) void k_fc1(
    const u16* __restrict__ h, const float* __restrict__ wT,
    const float* __restrict__ b1, float* __restrict__ out) {
  __shared__ float a_s[4][768];
  const int tid = threadIdx.x, rb = blockIdx.x * 4;
#pragma unroll
  for (int r = 0; r < 4; ++r) {
    const int row = rb + r, r16 = row & 15;
    for (int k = tid; k < 768; k += 256) {
      const int bt = k >> 6, kr = k & 63;
      const int idx = (bt * 512 + row) * 128 + (((kr >> 3) ^ r16) << 3) + (kr & 7);
      a_s[r][k] = bf2f(h[idx]) + bf2f(h[idx ^ 64]);
    }
  }
  __syncthreads();
  const int n = tid;
  float ac0 = b1[n], ac1 = ac0, ac2 = ac0, ac3 = ac0;
  for (int k0 = 0; k0 < 768; k0 += 8) {
    float w[8];
#pragma unroll
    for (int u = 0; u < 8; ++u) w[u] = wT[(k0 + u) * 256 + n];
#pragma unroll
    for (int u = 0; u < 8; ++u) {
      ac0 += a_s[0][k0 + u] * w[u];
      ac1 += a_s[1][k0 + u] * w[u];
      ac2 += a_s[2][k0 + u] * w[u];
      ac3 += a_s[3][k0 + u] * w[u];
    }
  }
  out[(rb + 0) * 256 + n] = fmaxf(ac0, 0.f);
  out[(rb + 1) * 256 + n] = fmaxf(ac1, 0.f);
  out[(rb + 2) * 256 + n] = fmaxf(ac2, 0.f);
  out[(rb + 3) * 256 + n] = fmaxf(ac3, 0.f);
}

__global__ __launch_bounds__(256) void k_fc2(
    const float* __restrict__ a, const float* __restrict__ w_fc2,
    const float* __restrict__ b_fc2, float* __restrict__ out) {
  const int lane = threadIdx.x & 63, w = threadIdx.x >> 6;
  const int b = blockIdx.x * 4 + w;
  const f32x4 av = ((const f32x4*)(a + b * 256))[lane];
#pragma unroll
  for (int c = 0; c < 10; ++c) {
    const f32x4 wv = ((const f32x4*)(w_fc2 + c * 256))[lane];
    float s = av[0] * wv[0] + av[1] * wv[1] + av[2] * wv[2] + av[3] * wv[3];
#pragma unroll
    for (int off = 32; off > 0; off >>= 1) s += __shfl_xor(s, off);
    if (lane == 0) out[b * 10 + c] = s + b_fc2[c];
  }
}

// ---------------- host ----------------
extern "C" void kernel_launch(void* const* d_in, const int* in_sizes, int n_in,
                              void* d_out, int out_size, void* d_ws, size_t ws_size,
                              hipStream_t stream) {
  const float* x     = (const float*)d_in[0];
  const float* w_ih  = (const float*)d_in[1];
  const float* w_hh  = (const float*)d_in[2];
  const float* b_ih  = (const float*)d_in[3];
  const float* b_hh  = (const float*)d_in[4];
  const float* w_fc1 = (const float*)d_in[5];
  const float* b_fc1 = (const float*)d_in[6];
  const float* w_fc2 = (const float*)d_in[7];
  const float* b_fc2 = (const float*)d_in[8];
  float* out = (float*)d_out;

  char* ws = (char*)d_ws;
  size_t off = 0;
  auto carve = [&](size_t bytes) {
    char* p = ws + off;
    off += (bytes + 255) & ~(size_t)255;
    return p;
  };
  u16*      Wg   = (u16*)carve(2064384ull * 2);         // 32*14*72*64 u16
  u16*      xpk  = (u16*)carve(16777216ull * 2);        // 128*2*512*128 u16
  u16*      hpkA = (u16*)carve(786432ull * 2);          // 12*512*128 u16
  u16*      hpkB = (u16*)carve(786432ull * 2);
  float*    fc1T = (float*)carve(768ull * 256 * 4);
  float*    fc1o = (float*)carve(512ull * 256 * 4);
  unsigned* bar  = (unsigned*)carve(1024);              // 8 x 64B counters
  if (off > ws_size) return;                            // ~42 MB needed

  k_prep_w<<<dim3(8064), dim3(256), 0, stream>>>(w_ih, w_hh, Wg);
  k_prep_x<<<dim3(65536), dim3(256), 0, stream>>>(x, xpk);
  k_prep_fc1t<<<dim3(768), dim3(256), 0, stream>>>(w_fc1, fc1T);
  hipMemsetAsync(hpkA, 0, 786432ull * 2, stream);       // h(0) = 0
  hipMemsetAsync(bar, 0, 1024, stream);                 // barrier counters

  void* kargs[] = {(void*)&Wg, (void*)&xpk, (void*)&hpkA, (void*)&hpkB,
                   (void*)&b_ih, (void*)&b_hh, (void*)&bar};
  hipLaunchCooperativeKernel((const void*)k_gru_all, dim3(256), dim3(512),
                             kargs, 0, stream);

  // t=127 (odd) wrote hpkA
  k_fc1<<<dim3(128), dim3(256), 0, stream>>>(hpkA, fc1T, b_fc1, fc1o);
  k_fc2<<<dim3(128), dim3(256), 0, stream>>>(fc1o, w_fc2, b_fc2, out);
}

// Round 5
// 1280.001 us; speedup vs baseline: 3.1759x; 3.1759x over previous
//
#include <hip/hip_runtime.h>
#include <hip/hip_bf16.h>

// GRU (B=512,T=128,I=128,H=768) + FC(768->256 relu ->10), fp32 in/out.
// Round 5: persistent kernel with XCD-LOCAL recurrence. Blocks self-organize
// by physical XCC_ID so each bg's 32 blocks share one XCD: h handoff lives in
// that XCD's L2 (producer write-through + consumer sc0 L1-bypass loads), NO
// per-step cache fences. Startup rendezvous verifies 32 blocks/XCD, else
// falls back to static mapping + full agent fences (correct anywhere).
// W resident in LDS; 2-buffer A pipeline; 2-pass split-precision bf16 MFMA.

typedef unsigned short u16;
typedef float    f32x4    __attribute__((ext_vector_type(4)));
typedef unsigned uint32x4 __attribute__((ext_vector_type(4)));
typedef __bf16   bf16x8   __attribute__((ext_vector_type(8)));

#define MFMA16 __builtin_amdgcn_mfma_f32_16x16x32_bf16

#define GLOAD16(gp, lp)                                                        \
  __builtin_amdgcn_global_load_lds(                                            \
      (const __attribute__((address_space(1))) void*)(gp),                     \
      (__attribute__((address_space(3))) void*)(lp), 16, 0, 0)
// sc0=1: bypass L1, read current L2 (cross-block h visibility within XCD)
#define GLOAD16C(gp, lp)                                                       \
  __builtin_amdgcn_global_load_lds(                                            \
      (const __attribute__((address_space(1))) void*)(gp),                     \
      (__attribute__((address_space(3))) void*)(lp), 16, 0, 1)

__device__ __forceinline__ float bf2f(u16 u) {
  unsigned v = ((unsigned)u) << 16;
  return __builtin_bit_cast(float, v);
}
__device__ __forceinline__ u16 f2bf(float f) {  // round-to-nearest-even
  unsigned x = __builtin_bit_cast(unsigned, f);
  unsigned r = (x + 0x7fffu + ((x >> 16) & 1u)) >> 16;
  return (u16)r;
}
__device__ __forceinline__ float sigm(float x) {
  x = fminf(fmaxf(x, -30.f), 30.f);
  return 1.f / (1.f + __expf(-x));
}
__device__ __forceinline__ float tanhx(float x) {
  x = fminf(fmaxf(x, -15.f), 15.f);
  float ex = __expf(2.f * x);
  return (ex - 1.f) / (ex + 1.f);
}

// ---------------- prep: pack + swizzle weights (hi bf16, 72 rows/body) -----
// Wg[jb][bt 0..13][r 0..71][c8][e] u16; r = g*24+c. slot c8 holds kc=c8^(r&7);
// k = bt*64+kc*8+e. k<768 -> w_hh[g*768+jb*24+c][k], else w_ih[...][k-768].
__global__ __launch_bounds__(256) void k_prep_w(
    const float* __restrict__ w_ih, const float* __restrict__ w_hh,
    u16* __restrict__ Wg) {
  int idx = blockIdx.x * 256 + threadIdx.x;     // < 32*14*72*64 = 2064384
  int e = idx & 7, c8 = (idx >> 3) & 7;
  int r3 = idx >> 6;
  int r = r3 % 72;
  int jbt = r3 / 72;
  int bt = jbt % 14, jb = jbt / 14;
  int kc = c8 ^ (r & 7);
  int k = bt * 64 + kc * 8 + e;
  int g = r / 24, c = r % 24;
  int grow = g * 768 + jb * 24 + c;
  float v = (k < 768) ? w_hh[grow * 768 + k] : w_ih[grow * 128 + (k - 768)];
  Wg[idx] = f2bf(v);
}

// xpk[t][bt' 0..1][row 0..511][c16][e] u16 (hi/lo 16-chunk, row&15 XOR)
__global__ __launch_bounds__(256) void k_prep_x(
    const float* __restrict__ x, u16* __restrict__ xpk) {
  int idx = blockIdx.x * 256 + threadIdx.x;     // < 128*2*512*128 = 16777216
  int e = idx & 7, c16 = (idx >> 3) & 15;
  int row = (idx >> 7) & 511;
  int tb = idx >> 16;
  int bt = tb & 1, t = tb >> 1;
  int lc = c16 ^ (row & 15);
  int hl = lc >> 3, kc = lc & 7;
  int i = bt * 64 + kc * 8 + e;
  float v = x[(row * 128 + t) * 128 + i];
  u16 h = f2bf(v);
  xpk[idx] = hl ? f2bf(v - bf2f(h)) : h;
}

// w_fc1T[k][n] = w_fc1[n][k]
__global__ __launch_bounds__(256) void k_prep_fc1t(
    const float* __restrict__ w_fc1, float* __restrict__ wT) {
  int idx = blockIdx.x * 256 + threadIdx.x;     // < 768*256
  int k = idx >> 8, n = idx & 255;
  wT[idx] = w_fc1[n * 768 + k];
}

// ---------------- persistent GRU kernel (all 128 timesteps) ----------------
// 256 blocks = (bg: 64 rows) x (jb: 24 h-cols), assigned DYNAMICALLY so that
// bg == physical XCD. 512 thr = 8 waves: mg = wv&3 (m-tile), sg = wv>>2.
__global__ __launch_bounds__(512) void k_gru_all(
    const u16* __restrict__ Wg, const u16* __restrict__ xpk,
    u16* __restrict__ hA, u16* __restrict__ hB,
    const float* __restrict__ b_ih, const float* __restrict__ b_hh,
    unsigned* __restrict__ bar, unsigned* __restrict__ ctl) {
  __shared__ __align__(16) u16 sW[64512];      // 126 KB: W slice, resident
  __shared__ __align__(16) u16 sA[2][8192];    // 2 x 16 KB: A double buffer
  __shared__ unsigned s_asn;
  const int tid = threadIdx.x;
  const int lane = tid & 63, wv = tid >> 6;
  const int mg = wv & 3, sg = wv >> 2;
  const int l15 = lane & 15, lg = lane >> 4;

  // ---- startup: self-organize by physical XCD (G16-safe w/ fallback) ----
  if (tid == 0) {
    unsigned xcd;
    asm volatile("s_getreg_b32 %0, hwreg(HW_REG_XCC_ID, 0, 32)" : "=s"(xcd));
    xcd &= 7u;
    unsigned slot = __hip_atomic_fetch_add(&ctl[xcd * 32], 1u,
        __ATOMIC_RELAXED, __HIP_MEMORY_SCOPE_AGENT);
    __hip_atomic_fetch_add(&ctl[256], 1u, __ATOMIC_RELEASE,
                           __HIP_MEMORY_SCOPE_AGENT);
    while (__hip_atomic_load(&ctl[256], __ATOMIC_RELAXED,
                             __HIP_MEMORY_SCOPE_AGENT) < 256u)
      __builtin_amdgcn_s_sleep(8);
    __builtin_amdgcn_fence(__ATOMIC_ACQUIRE, "agent");
    bool ok = (slot < 32u);
    for (int xx = 0; xx < 8; ++xx)
      ok &= (__hip_atomic_load(&ctl[xx * 32], __ATOMIC_RELAXED,
                               __HIP_MEMORY_SCOPE_AGENT) == 32u);
    unsigned bgv, jbv, fen;
    if (ok) { bgv = xcd; jbv = slot; fen = 0u; }
    else    { bgv = (unsigned)blockIdx.x >> 5;
              jbv = (unsigned)blockIdx.x & 31u; fen = 1u; }
    s_asn = bgv | (jbv << 3) | (fen << 8);
  }
  __syncthreads();
  const unsigned asn = s_asn;
  const int bg = asn & 7, jb = (asn >> 3) & 31;
  const bool fence = (asn >> 8) & 1;
  const int mbase = bg * 64;

  // ---- load W slice into LDS once (126 chunks of 1 KB) ----
  {
    const u16* wbase = Wg + (size_t)jb * 64512;
    for (int ch = wv; ch < 126; ch += 8)
      GLOAD16(wbase + ch * 512 + lane * 8, &sW[ch * 512]);
  }
  asm volatile("s_waitcnt vmcnt(0)" ::: "memory");
  __syncthreads();

  // ---- precomputed fragment offsets (u16 units) ----
  const int cc = sg * 16 + l15;
  const int ccv = (cc < 24) ? cc : (cc - 8);   // invalid lanes alias rows
  int aOff[2][2], bOff[3][2];
#pragma unroll
  for (int kk = 0; kk < 2; ++kk) {
    const int sw = (((kk << 2) + lg) ^ (l15 & 7)) << 3;
#pragma unroll
    for (int hl = 0; hl < 2; ++hl)
      aOff[kk][hl] = (mg * 16 + l15) * 128 +
                     ((((hl << 3) + (kk << 2) + lg) ^ l15) << 3);
#pragma unroll
    for (int g = 0; g < 3; ++g)
      bOff[g][kk] = (g * 24 + ccv) * 64 + sw;
  }
  const int schunk = wv * 2;                   // this wave's 2 staging chunks

  // epilogue constants
  const int j = jb * 24 + cc;                  // may be >= valid; guarded
  const bool jvalid = (cc < 24);
  float br = 0.f, bz = 0.f, bni = 0.f, bnh = 0.f;
  if (jvalid) {
    br = b_ih[j] + b_hh[j];
    bz = b_ih[768 + j] + b_hh[768 + j];
    bni = b_ih[1536 + j]; bnh = b_hh[1536 + j];
  }
  const int ebt = j >> 6, ekr = j & 63;
  const int ekc = ekr >> 3, eke = ekr & 7;
  unsigned* mybar = bar + bg * 32;             // 128B-strided counters

#pragma unroll 1
  for (int t = 0; t < 128; ++t) {
    const u16* hcur = (t & 1) ? hB : hA;
    u16* hnxt = (t & 1) ? hA : hB;
    const u16* xpt = xpk + (size_t)t * 131072;
    const u16* hsl = hcur + mbase * 128;
    const u16* xsl = xpt + mbase * 128;

    f32x4 acc0 = {0.f, 0.f, 0.f, 0.f};  // r
    f32x4 acc1 = {0.f, 0.f, 0.f, 0.f};  // z
    f32x4 acc2 = {0.f, 0.f, 0.f, 0.f};  // n (h-part)
    f32x4 acc3 = {0.f, 0.f, 0.f, 0.f};  // n (x-part)

    // prologue: stage body 0 (h -> sc0 loads)
    GLOAD16C(hsl + schunk * 512 + lane * 8, &sA[0][schunk * 512]);
    GLOAD16C(hsl + (schunk + 1) * 512 + lane * 8, &sA[0][(schunk + 1) * 512]);
    asm volatile("s_waitcnt vmcnt(0)" ::: "memory");
    __builtin_amdgcn_s_barrier();
    asm volatile("" ::: "memory");

#pragma unroll
    for (int bt = 0; bt < 14; ++bt) {
      const int buf = bt & 1;
      if (bt < 13) {                    // stage next body (issued early)
        const int nt = bt + 1;
        if (nt < 12) {
          const u16* ab = hsl + nt * 65536;
          GLOAD16C(ab + schunk * 512 + lane * 8, &sA[buf ^ 1][schunk * 512]);
          GLOAD16C(ab + (schunk + 1) * 512 + lane * 8,
                   &sA[buf ^ 1][(schunk + 1) * 512]);
        } else {
          const u16* ab = xsl + (nt - 12) * 65536;
          GLOAD16(ab + schunk * 512 + lane * 8, &sA[buf ^ 1][schunk * 512]);
          GLOAD16(ab + (schunk + 1) * 512 + lane * 8,
                  &sA[buf ^ 1][(schunk + 1) * 512]);
        }
      }
      bf16x8 Ah[2], Al[2], Bf[3][2];
#pragma unroll
      for (int kk = 0; kk < 2; ++kk) {
        Ah[kk] = *(const bf16x8*)&sA[buf][aOff[kk][0]];
        Al[kk] = *(const bf16x8*)&sA[buf][aOff[kk][1]];
#pragma unroll
        for (int g = 0; g < 3; ++g)
          Bf[g][kk] = *(const bf16x8*)&sW[bt * 4608 + bOff[g][kk]];
      }
      __builtin_amdgcn_s_setprio(1);
#pragma unroll
      for (int kk = 0; kk < 2; ++kk)
#pragma unroll
        for (int ps = 0; ps < 2; ++ps) {
          const bf16x8 Aop = ps ? Al[kk] : Ah[kk];
          acc0 = MFMA16(Aop, Bf[0][kk], acc0, 0, 0, 0);
          acc1 = MFMA16(Aop, Bf[1][kk], acc1, 0, 0, 0);
          if (bt < 12) acc2 = MFMA16(Aop, Bf[2][kk], acc2, 0, 0, 0);
          else         acc3 = MFMA16(Aop, Bf[2][kk], acc3, 0, 0, 0);
        }
      __builtin_amdgcn_s_setprio(0);
      if (bt < 13) {
        asm volatile("s_waitcnt vmcnt(0)" ::: "memory");
        __builtin_amdgcn_s_barrier();
        asm volatile("" ::: "memory");
      }
    }

    // ---- epilogue: gates + h update. C layout: col=lane&15, row=lg*4+e
    if (jvalid) {
#pragma unroll
      for (int e = 0; e < 4; ++e) {
        const int row = mbase + mg * 16 + lg * 4 + e;
        const int hidx = (ebt * 512 + row) * 128 + ((ekc ^ (row & 15)) << 3) + eke;
        const float hold = bf2f(hcur[hidx]) + bf2f(hcur[hidx ^ 64]);
        const float rg = sigm(acc0[e] + br);
        const float zg = sigm(acc1[e] + bz);
        const float ng = tanhx(acc3[e] + bni + rg * (acc2[e] + bnh));
        const float hv = (1.f - zg) * ng + zg * hold;
        const u16 uh = f2bf(hv);
        hnxt[hidx] = uh;
        hnxt[hidx ^ 64] = f2bf(hv - bf2f(uh));
      }
    }

    if (t == 127) break;               // final h consumed by k_fc1 after end

    // ---- inter-block step barrier (32 blocks of this bg, same XCD) ----
    __syncthreads();                   // all waves' stores drained into L2
    if (fence) __builtin_amdgcn_fence(__ATOMIC_RELEASE, "agent");
    if (tid == 0) {
      __hip_atomic_fetch_add(mybar, 1u, __ATOMIC_RELAXED,
                             __HIP_MEMORY_SCOPE_AGENT);
      const unsigned tgt = 32u * (unsigned)(t + 1);
      while (__hip_atomic_load(mybar, __ATOMIC_RELAXED,
                               __HIP_MEMORY_SCOPE_AGENT) < tgt)
        __builtin_amdgcn_s_sleep(2);
    }
    __syncthreads();
    if (fence) __builtin_amdgcn_fence(__ATOMIC_ACQUIRE, "agent");
  }
}

// ---------------- FC tail (fp32) ----------------
__global__ __launch_bounds__(256) void k_fc1(
    const u16* __restrict__ h, const float* __restrict__ wT,
    const float* __restrict__ b1, float* __restrict__ out) {
  __shared__ float a_s[4][768];
  const int tid = threadIdx.x, rb = blockIdx.x * 4;
#pragma unroll
  for (int r = 0; r < 4; ++r) {
    const int row = rb + r, r16 = row & 15;
    for (int k = tid; k < 768; k += 256) {
      const int bt = k >> 6, kr = k & 63;
      const int idx = (bt * 512 + row) * 128 + (((kr >> 3) ^ r16) << 3) + (kr & 7);
      a_s[r][k] = bf2f(h[idx]) + bf2f(h[idx ^ 64]);
    }
  }
  __syncthreads();
  const int n = tid;
  float ac0 = b1[n], ac1 = ac0, ac2 = ac0, ac3 = ac0;
  for (int k0 = 0; k0 < 768; k0 += 8) {
    float w[8];
#pragma unroll
    for (int u = 0; u < 8; ++u) w[u] = wT[(k0 + u) * 256 + n];
#pragma unroll
    for (int u = 0; u < 8; ++u) {
      ac0 += a_s[0][k0 + u] * w[u];
      ac1 += a_s[1][k0 + u] * w[u];
      ac2 += a_s[2][k0 + u] * w[u];
      ac3 += a_s[3][k0 + u] * w[u];
    }
  }
  out[(rb + 0) * 256 + n] = fmaxf(ac0, 0.f);
  out[(rb + 1) * 256 + n] = fmaxf(ac1, 0.f);
  out[(rb + 2) * 256 + n] = fmaxf(ac2, 0.f);
  out[(rb + 3) * 256 + n] = fmaxf(ac3, 0.f);
}

__global__ __launch_bounds__(256) void k_fc2(
    const float* __restrict__ a, const float* __restrict__ w_fc2,
    const float* __restrict__ b_fc2, float* __restrict__ out) {
  const int lane = threadIdx.x & 63, w = threadIdx.x >> 6;
  const int b = blockIdx.x * 4 + w;
  const f32x4 av = ((const f32x4*)(a + b * 256))[lane];
#pragma unroll
  for (int c = 0; c < 10; ++c) {
    const f32x4 wv = ((const f32x4*)(w_fc2 + c * 256))[lane];
    float s = av[0] * wv[0] + av[1] * wv[1] + av[2] * wv[2] + av[3] * wv[3];
#pragma unroll
    for (int off = 32; off > 0; off >>= 1) s += __shfl_xor(s, off);
    if (lane == 0) out[b * 10 + c] = s + b_fc2[c];
  }
}

// ---------------- host ----------------
extern "C" void kernel_launch(void* const* d_in, const int* in_sizes, int n_in,
                              void* d_out, int out_size, void* d_ws, size_t ws_size,
                              hipStream_t stream) {
  const float* x     = (const float*)d_in[0];
  const float* w_ih  = (const float*)d_in[1];
  const float* w_hh  = (const float*)d_in[2];
  const float* b_ih  = (const float*)d_in[3];
  const float* b_hh  = (const float*)d_in[4];
  const float* w_fc1 = (const float*)d_in[5];
  const float* b_fc1 = (const float*)d_in[6];
  const float* w_fc2 = (const float*)d_in[7];
  const float* b_fc2 = (const float*)d_in[8];
  float* out = (float*)d_out;

  char* ws = (char*)d_ws;
  size_t off = 0;
  auto carve = [&](size_t bytes) {
    char* p = ws + off;
    off += (bytes + 255) & ~(size_t)255;
    return p;
  };
  u16*      Wg   = (u16*)carve(2064384ull * 2);         // 32*14*72*64 u16
  u16*      xpk  = (u16*)carve(16777216ull * 2);        // 128*2*512*128 u16
  u16*      hpkA = (u16*)carve(786432ull * 2);          // 12*512*128 u16
  u16*      hpkB = (u16*)carve(786432ull * 2);
  float*    fc1T = (float*)carve(768ull * 256 * 4);
  float*    fc1o = (float*)carve(512ull * 256 * 4);
  unsigned* bar  = (unsigned*)carve(4096);              // 8 x 128B counters
  unsigned* ctl  = (unsigned*)carve(4096);              // xcd cnts + gbar
  if (off > ws_size) return;                            // ~42 MB needed

  k_prep_w<<<dim3(8064), dim3(256), 0, stream>>>(w_ih, w_hh, Wg);
  k_prep_x<<<dim3(65536), dim3(256), 0, stream>>>(x, xpk);
  k_prep_fc1t<<<dim3(768), dim3(256), 0, stream>>>(w_fc1, fc1T);
  hipMemsetAsync(hpkA, 0, 786432ull * 2, stream);       // h(0) = 0
  hipMemsetAsync(bar, 0, 4096, stream);                 // step barrier counters
  hipMemsetAsync(ctl, 0, 4096, stream);                 // startup rendezvous

  void* kargs[] = {(void*)&Wg, (void*)&xpk, (void*)&hpkA, (void*)&hpkB,
                   (void*)&b_ih, (void*)&b_hh, (void*)&bar, (void*)&ctl};
  hipLaunchCooperativeKernel((const void*)k_gru_all, dim3(256), dim3(512),
                             kargs, 0, stream);

  // t=127 (odd) wrote hpkA
  k_fc1<<<dim3(128), dim3(256), 0, stream>>>(hpkA, fc1T, b_fc1, fc1o);
  k_fc2<<<dim3(128), dim3(256), 0, stream>>>(fc1o, w_fc2, b_fc2, out);
}

// Round 6
// 1104.760 us; speedup vs baseline: 3.6796x; 1.1586x over previous
//
#include <hip/hip_runtime.h>
#include <hip/hip_bf16.h>

// GRU (B=512,T=128,I=128,H=768) + FC(768->256 relu ->10), fp32 in/out.
// Round 6: persistent XCD-local kernel + counted-vmcnt 3-buffer A pipeline
// (stage 2 bodies ahead; per-body wait vmcnt(2) THEN barrier -> all waves'
// chunks proven landed; no vmcnt(0) drains in main loop). x-body W moved to
// VGPRs (48 regs) so LDS fits: sW 108 KB + 3x16 KB A. Body order
// [x0,x1,h0..h11]; next-step x staged across the step barrier (stores drained
// by counted vmcnt, x loads stay in flight through the spin).

typedef unsigned short u16;
typedef float    f32x4    __attribute__((ext_vector_type(4)));
typedef unsigned uint32x4 __attribute__((ext_vector_type(4)));
typedef __bf16   bf16x8   __attribute__((ext_vector_type(8)));

#define MFMA16 __builtin_amdgcn_mfma_f32_16x16x32_bf16

#define GLOAD16(gp, lp)                                                        \
  __builtin_amdgcn_global_load_lds(                                            \
      (const __attribute__((address_space(1))) void*)(gp),                     \
      (__attribute__((address_space(3))) void*)(lp), 16, 0, 0)
// sc0=1: bypass L1, read current L2 (cross-block h visibility within XCD)
#define GLOAD16C(gp, lp)                                                       \
  __builtin_amdgcn_global_load_lds(                                            \
      (const __attribute__((address_space(1))) void*)(gp),                     \
      (__attribute__((address_space(3))) void*)(lp), 16, 0, 1)

__device__ __forceinline__ float bf2f(u16 u) {
  unsigned v = ((unsigned)u) << 16;
  return __builtin_bit_cast(float, v);
}
__device__ __forceinline__ u16 f2bf(float f) {  // round-to-nearest-even
  unsigned x = __builtin_bit_cast(unsigned, f);
  unsigned r = (x + 0x7fffu + ((x >> 16) & 1u)) >> 16;
  return (u16)r;
}
__device__ __forceinline__ float sigm(float x) {
  x = fminf(fmaxf(x, -30.f), 30.f);
  return __builtin_amdgcn_rcpf(1.f + __expf(-x));
}
__device__ __forceinline__ float tanhx(float x) {
  x = fminf(fmaxf(x, -15.f), 15.f);
  float ex = __expf(2.f * x);
  return (ex - 1.f) * __builtin_amdgcn_rcpf(ex + 1.f);
}

// ---------------- prep: pack + swizzle weights (hi bf16, 72 rows/body) -----
// Wg[jb][bt 0..13][r 0..71][c8][e] u16; r = g*24+c. slot c8 holds kc=c8^(r&7);
// k = bt*64+kc*8+e. k<768 -> w_hh[g*768+jb*24+c][k], else w_ih[...][k-768].
__global__ __launch_bounds__(256) void k_prep_w(
    const float* __restrict__ w_ih, const float* __restrict__ w_hh,
    u16* __restrict__ Wg) {
  int idx = blockIdx.x * 256 + threadIdx.x;     // < 32*14*72*64 = 2064384
  int e = idx & 7, c8 = (idx >> 3) & 7;
  int r3 = idx >> 6;
  int r = r3 % 72;
  int jbt = r3 / 72;
  int bt = jbt % 14, jb = jbt / 14;
  int kc = c8 ^ (r & 7);
  int k = bt * 64 + kc * 8 + e;
  int g = r / 24, c = r % 24;
  int grow = g * 768 + jb * 24 + c;
  float v = (k < 768) ? w_hh[grow * 768 + k] : w_ih[grow * 128 + (k - 768)];
  Wg[idx] = f2bf(v);
}

// xpk[t][bt' 0..1][row 0..511][c16][e] u16 (hi/lo 16-chunk, row&15 XOR)
__global__ __launch_bounds__(256) void k_prep_x(
    const float* __restrict__ x, u16* __restrict__ xpk) {
  int idx = blockIdx.x * 256 + threadIdx.x;     // < 128*2*512*128 = 16777216
  int e = idx & 7, c16 = (idx >> 3) & 15;
  int row = (idx >> 7) & 511;
  int tb = idx >> 16;
  int bt = tb & 1, t = tb >> 1;
  int lc = c16 ^ (row & 15);
  int hl = lc >> 3, kc = lc & 7;
  int i = bt * 64 + kc * 8 + e;
  float v = x[(row * 128 + t) * 128 + i];
  u16 h = f2bf(v);
  xpk[idx] = hl ? f2bf(v - bf2f(h)) : h;
}

// w_fc1T[k][n] = w_fc1[n][k]
__global__ __launch_bounds__(256) void k_prep_fc1t(
    const float* __restrict__ w_fc1, float* __restrict__ wT) {
  int idx = blockIdx.x * 256 + threadIdx.x;     // < 768*256
  int k = idx >> 8, n = idx & 255;
  wT[idx] = w_fc1[n * 768 + k];
}

// ---------------- persistent GRU kernel (all 128 timesteps) ----------------
// 256 blocks = (bg: 64 rows) x (jb: 24 h-cols), bg == physical XCD via
// startup rendezvous. 512 thr = 8 waves: mg = wv&3 (m-tile), sg = wv>>2.
// Bodies b: 0,1 = x-part (W in VGPRs, acc3); 2..13 = h-part (W in LDS, acc2).
__global__ __launch_bounds__(512) void k_gru_all(
    const u16* __restrict__ Wg, const u16* __restrict__ xpk,
    u16* __restrict__ hA, u16* __restrict__ hB,
    const float* __restrict__ b_ih, const float* __restrict__ b_hh,
    unsigned* __restrict__ bar, unsigned* __restrict__ ctl) {
  __shared__ __align__(16) u16 sW[55296];      // 108 KB: h-part W, resident
  __shared__ __align__(16) u16 sA[3][8192];    // 3 x 16 KB: A ring buffer
  __shared__ unsigned s_asn;
  const int tid = threadIdx.x;
  const int lane = tid & 63, wv = tid >> 6;
  const int mg = wv & 3, sg = wv >> 2;
  const int l15 = lane & 15, lg = lane >> 4;

  // ---- startup: self-organize by physical XCD (G16-safe w/ fallback) ----
  if (tid == 0) {
    unsigned xcd;
    asm volatile("s_getreg_b32 %0, hwreg(HW_REG_XCC_ID, 0, 32)" : "=s"(xcd));
    xcd &= 7u;
    unsigned slot = __hip_atomic_fetch_add(&ctl[xcd * 32], 1u,
        __ATOMIC_RELAXED, __HIP_MEMORY_SCOPE_AGENT);
    __hip_atomic_fetch_add(&ctl[256], 1u, __ATOMIC_RELEASE,
                           __HIP_MEMORY_SCOPE_AGENT);
    while (__hip_atomic_load(&ctl[256], __ATOMIC_RELAXED,
                             __HIP_MEMORY_SCOPE_AGENT) < 256u)
      __builtin_amdgcn_s_sleep(8);
    __builtin_amdgcn_fence(__ATOMIC_ACQUIRE, "agent");
    bool ok = (slot < 32u);
    for (int xx = 0; xx < 8; ++xx)
      ok &= (__hip_atomic_load(&ctl[xx * 32], __ATOMIC_RELAXED,
                               __HIP_MEMORY_SCOPE_AGENT) == 32u);
    unsigned bgv, jbv, fen;
    if (ok) { bgv = xcd; jbv = slot; fen = 0u; }
    else    { bgv = (unsigned)blockIdx.x >> 5;
              jbv = (unsigned)blockIdx.x & 31u; fen = 1u; }
    s_asn = bgv | (jbv << 3) | (fen << 8);
  }
  __syncthreads();
  const unsigned asn = s_asn;
  const int bg = asn & 7, jb = (asn >> 3) & 31;
  const bool fence = (asn >> 8) & 1;
  const int mbase = bg * 64;

  // ---- fragment offsets (u16 units) ----
  const int cc = sg * 16 + l15;
  const int ccv = (cc < 24) ? cc : (cc - 8);   // invalid lanes alias rows
  int aOff[2][2], bOff[3][2];
#pragma unroll
  for (int kk = 0; kk < 2; ++kk) {
    const int sw = (((kk << 2) + lg) ^ (l15 & 7)) << 3;
#pragma unroll
    for (int hl = 0; hl < 2; ++hl)
      aOff[kk][hl] = (mg * 16 + l15) * 128 +
                     ((((hl << 3) + (kk << 2) + lg) ^ l15) << 3);
#pragma unroll
    for (int g = 0; g < 3; ++g)
      bOff[g][kk] = (g * 24 + ccv) * 64 + sw;
  }
  const int schunk = wv * 2;                   // this wave's 2 staging chunks

  // ---- load h-part W (bodies 0..11) into LDS once; x-part W into VGPRs ----
  const u16* wbase = Wg + (size_t)jb * 64512;
  for (int ch = wv; ch < 108; ch += 8)
    GLOAD16(wbase + ch * 512 + lane * 8, &sW[ch * 512]);
  bf16x8 Bx[2][3][2];                          // [xbody][gate][kk] 48 VGPR
#pragma unroll
  for (int xb = 0; xb < 2; ++xb)
#pragma unroll
    for (int g = 0; g < 3; ++g)
#pragma unroll
      for (int kk = 0; kk < 2; ++kk)
        Bx[xb][g][kk] = __builtin_bit_cast(bf16x8,
            *(const uint32x4*)(wbase + (12 + xb) * 4608 + bOff[g][kk]));
  asm volatile("s_waitcnt vmcnt(0)" ::: "memory");
  __syncthreads();

  // epilogue constants
  const int j = jb * 24 + cc;                  // may be >= valid; guarded
  const bool jvalid = (cc < 24);
  float br = 0.f, bz = 0.f, bni = 0.f, bnh = 0.f;
  if (jvalid) {
    br = b_ih[j] + b_hh[j];
    bz = b_ih[768 + j] + b_hh[768 + j];
    bni = b_ih[1536 + j]; bnh = b_hh[1536 + j];
  }
  const int ebt = j >> 6, ekr = j & 63;
  const int ekc = ekr >> 3, eke = ekr & 7;
  unsigned* mybar = bar + bg * 32;             // 128B-strided counters

  // ---- pre-stage x bodies (b=0,1) of step t=0 ----
  {
    const u16* xn = xpk + (size_t)mbase * 128;
    GLOAD16(xn + schunk * 512 + lane * 8, &sA[0][schunk * 512]);
    GLOAD16(xn + (schunk + 1) * 512 + lane * 8, &sA[0][(schunk + 1) * 512]);
    GLOAD16(xn + 65536 + schunk * 512 + lane * 8, &sA[1][schunk * 512]);
    GLOAD16(xn + 65536 + (schunk + 1) * 512 + lane * 8,
            &sA[1][(schunk + 1) * 512]);
  }

#pragma unroll 1
  for (int t = 0; t < 128; ++t) {
    const u16* hcur = (t & 1) ? hB : hA;
    u16* hnxt = (t & 1) ? hA : hB;
    const u16* hsl = hcur + mbase * 128;

    f32x4 acc0 = {0.f, 0.f, 0.f, 0.f};  // r
    f32x4 acc1 = {0.f, 0.f, 0.f, 0.f};  // z
    f32x4 acc2 = {0.f, 0.f, 0.f, 0.f};  // n (h-part)
    f32x4 acc3 = {0.f, 0.f, 0.f, 0.f};  // n (x-part)

    // ---- body loop: b=0,1 x-part; b=2..13 h-part. Counted-vmcnt pipeline:
    // stage(b) issued at body b-2; wait own vmcnt(2) THEN barrier => all
    // waves' chunks landed AND buf (b+2)%3 free for stage(b+2).
#pragma unroll
    for (int b = 0; b < 14; ++b) {
      if (b < 13) asm volatile("s_waitcnt vmcnt(2)" ::: "memory");
      else        asm volatile("s_waitcnt vmcnt(0)" ::: "memory");
      __builtin_amdgcn_s_barrier();
      asm volatile("" ::: "memory");
      if (b + 2 < 14) {                 // stage(b+2): always h (b+2 >= 2)
        const u16* ab = hsl + b * 65536;         // h body (b+2)-2 = b
        const int nbuf = (b + 2) % 3;
        GLOAD16C(ab + schunk * 512 + lane * 8, &sA[nbuf][schunk * 512]);
        GLOAD16C(ab + (schunk + 1) * 512 + lane * 8,
                 &sA[nbuf][(schunk + 1) * 512]);
      }
      const int buf = b % 3;
      bf16x8 Ah[2], Al[2];
#pragma unroll
      for (int kk = 0; kk < 2; ++kk) {
        Ah[kk] = *(const bf16x8*)&sA[buf][aOff[kk][0]];
        Al[kk] = *(const bf16x8*)&sA[buf][aOff[kk][1]];
      }
      if (b < 2) {                      // x body: W from VGPRs -> acc3
        __builtin_amdgcn_s_setprio(1);
#pragma unroll
        for (int kk = 0; kk < 2; ++kk)
#pragma unroll
          for (int ps = 0; ps < 2; ++ps) {
            const bf16x8 Aop = ps ? Al[kk] : Ah[kk];
            acc0 = MFMA16(Aop, Bx[b][0][kk], acc0, 0, 0, 0);
            acc1 = MFMA16(Aop, Bx[b][1][kk], acc1, 0, 0, 0);
            acc3 = MFMA16(Aop, Bx[b][2][kk], acc3, 0, 0, 0);
          }
        __builtin_amdgcn_s_setprio(0);
      } else {                          // h body: W from LDS -> acc2
        bf16x8 Bf[3][2];
#pragma unroll
        for (int kk = 0; kk < 2; ++kk)
#pragma unroll
          for (int g = 0; g < 3; ++g)
            Bf[g][kk] = *(const bf16x8*)&sW[(b - 2) * 4608 + bOff[g][kk]];
        __builtin_amdgcn_s_setprio(1);
#pragma unroll
        for (int kk = 0; kk < 2; ++kk)
#pragma unroll
          for (int ps = 0; ps < 2; ++ps) {
            const bf16x8 Aop = ps ? Al[kk] : Ah[kk];
            acc0 = MFMA16(Aop, Bf[0][kk], acc0, 0, 0, 0);
            acc1 = MFMA16(Aop, Bf[1][kk], acc1, 0, 0, 0);
            acc2 = MFMA16(Aop, Bf[2][kk], acc2, 0, 0, 0);
          }
        __builtin_amdgcn_s_setprio(0);
      }
    }

    // ---- epilogue: gates + h update. C layout: col=lane&15, row=lg*4+e
    if (jvalid) {
#pragma unroll
      for (int e = 0; e < 4; ++e) {
        const int row = mbase + mg * 16 + lg * 4 + e;
        const int hidx = (ebt * 512 + row) * 128 + ((ekc ^ (row & 15)) << 3) + eke;
        const float hold = bf2f(hcur[hidx]) + bf2f(hcur[hidx ^ 64]);
        const float rg = sigm(acc0[e] + br);
        const float zg = sigm(acc1[e] + bz);
        const float ng = tanhx(acc3[e] + bni + rg * (acc2[e] + bnh));
        const float hv = (1.f - zg) * ng + zg * hold;
        const u16 uh = f2bf(hv);
        hnxt[hidx] = uh;
        hnxt[hidx ^ 64] = f2bf(hv - bf2f(uh));
      }
    }

    if (t == 127) break;               // final h consumed by k_fc1 after end

    // ---- step boundary: stage next-step x across the barrier ----
    const u16* xn = xpk + (size_t)(t + 1) * 131072 + mbase * 128;
    // stage(0)->buf0 (free: body 12 used buf0, proven read by body-13 barrier)
    GLOAD16(xn + schunk * 512 + lane * 8, &sA[0][schunk * 512]);
    // drain epilogue stores (8 loads+8 stores oldest), keep stage(0) in flight
    asm volatile("s_waitcnt vmcnt(2)" ::: "memory");
    if (fence) __builtin_amdgcn_fence(__ATOMIC_RELEASE, "agent");
    __builtin_amdgcn_s_barrier();      // all stores drained, all past body 13
    asm volatile("" ::: "memory");
    // stage(1)->buf1 (free now: all waves past body-13 reads)
    GLOAD16(xn + 65536 + schunk * 512 + lane * 8, &sA[1][schunk * 512]);
    GLOAD16(xn + 65536 + (schunk + 1) * 512 + lane * 8,
            &sA[1][(schunk + 1) * 512]);
    GLOAD16(xn + (schunk + 1) * 512 + lane * 8, &sA[0][(schunk + 1) * 512]);
    if (tid == 0) {
      __hip_atomic_fetch_add(mybar, 1u, __ATOMIC_RELAXED,
                             __HIP_MEMORY_SCOPE_AGENT);
      const unsigned tgt = 32u * (unsigned)(t + 1);
      while (__hip_atomic_load(mybar, __ATOMIC_RELAXED,
                               __HIP_MEMORY_SCOPE_AGENT) < tgt)
        __builtin_amdgcn_s_sleep(2);
    }
    __builtin_amdgcn_s_barrier();      // h(t+1) fully published (same XCD)
    asm volatile("" ::: "memory");
    if (fence) __builtin_amdgcn_fence(__ATOMIC_ACQUIRE, "agent");
    if (wv == 0)                       // renormalize wave0's vmcnt (atomics)
      asm volatile("s_waitcnt vmcnt(0)" ::: "memory");
  }
}

// ---------------- FC tail (fp32) ----------------
__global__ __launch_bounds__(256) void k_fc1(
    const u16* __restrict__ h, const float* __restrict__ wT,
    const float* __restrict__ b1, float* __restrict__ out) {
  __shared__ float a_s[4][768];
  const int tid = threadIdx.x, rb = blockIdx.x * 4;
#pragma unroll
  for (int r = 0; r < 4; ++r) {
    const int row = rb + r, r16 = row & 15;
    for (int k = tid; k < 768; k += 256) {
      const int bt = k >> 6, kr = k & 63;
      const int idx = (bt * 512 + row) * 128 + (((kr >> 3) ^ r16) << 3) + (kr & 7);
      a_s[r][k] = bf2f(h[idx]) + bf2f(h[idx ^ 64]);
    }
  }
  __syncthreads();
  const int n = tid;
  float ac0 = b1[n], ac1 = ac0, ac2 = ac0, ac3 = ac0;
  for (int k0 = 0; k0 < 768; k0 += 8) {
    float w[8];
#pragma unroll
    for (int u = 0; u < 8; ++u) w[u] = wT[(k0 + u) * 256 + n];
#pragma unroll
    for (int u = 0; u < 8; ++u) {
      ac0 += a_s[0][k0 + u] * w[u];
      ac1 += a_s[1][k0 + u] * w[u];
      ac2 += a_s[2][k0 + u] * w[u];
      ac3 += a_s[3][k0 + u] * w[u];
    }
  }
  out[(rb + 0) * 256 + n] = fmaxf(ac0, 0.f);
  out[(rb + 1) * 256 + n] = fmaxf(ac1, 0.f);
  out[(rb + 2) * 256 + n] = fmaxf(ac2, 0.f);
  out[(rb + 3) * 256 + n] = fmaxf(ac3, 0.f);
}

__global__ __launch_bounds__(256) void k_fc2(
    const float* __restrict__ a, const float* __restrict__ w_fc2,
    const float* __restrict__ b_fc2, float* __restrict__ out) {
  const int lane = threadIdx.x & 63, w = threadIdx.x >> 6;
  const int b = blockIdx.x * 4 + w;
  const f32x4 av = ((const f32x4*)(a + b * 256))[lane];
#pragma unroll
  for (int c = 0; c < 10; ++c) {
    const f32x4 wv = ((const f32x4*)(w_fc2 + c * 256))[lane];
    float s = av[0] * wv[0] + av[1] * wv[1] + av[2] * wv[2] + av[3] * wv[3];
#pragma unroll
    for (int off = 32; off > 0; off >>= 1) s += __shfl_xor(s, off);
    if (lane == 0) out[b * 10 + c] = s + b_fc2[c];
  }
}

// ---------------- host ----------------
extern "C" void kernel_launch(void* const* d_in, const int* in_sizes, int n_in,
                              void* d_out, int out_size, void* d_ws, size_t ws_size,
                              hipStream_t stream) {
  const float* x     = (const float*)d_in[0];
  const float* w_ih  = (const float*)d_in[1];
  const float* w_hh  = (const float*)d_in[2];
  const float* b_ih  = (const float*)d_in[3];
  const float* b_hh  = (const float*)d_in[4];
  const float* w_fc1 = (const float*)d_in[5];
  const float* b_fc1 = (const float*)d_in[6];
  const float* w_fc2 = (const float*)d_in[7];
  const float* b_fc2 = (const float*)d_in[8];
  float* out = (float*)d_out;

  char* ws = (char*)d_ws;
  size_t off = 0;
  auto carve = [&](size_t bytes) {
    char* p = ws + off;
    off += (bytes + 255) & ~(size_t)255;
    return p;
  };
  u16*      Wg   = (u16*)carve(2064384ull * 2);         // 32*14*72*64 u16
  u16*      xpk  = (u16*)carve(16777216ull * 2);        // 128*2*512*128 u16
  u16*      hpkA = (u16*)carve(786432ull * 2);          // 12*512*128 u16
  u16*      hpkB = (u16*)carve(786432ull * 2);
  float*    fc1T = (float*)carve(768ull * 256 * 4);
  float*    fc1o = (float*)carve(512ull * 256 * 4);
  unsigned* bar  = (unsigned*)carve(4096);              // 8 x 128B counters
  unsigned* ctl  = (unsigned*)carve(4096);              // xcd cnts + gbar
  if (off > ws_size) return;                            // ~42 MB needed

  k_prep_w<<<dim3(8064), dim3(256), 0, stream>>>(w_ih, w_hh, Wg);
  k_prep_x<<<dim3(65536), dim3(256), 0, stream>>>(x, xpk);
  k_prep_fc1t<<<dim3(768), dim3(256), 0, stream>>>(w_fc1, fc1T);
  hipMemsetAsync(hpkA, 0, 786432ull * 2, stream);       // h(0) = 0
  hipMemsetAsync(bar, 0, 4096, stream);                 // step barrier counters
  hipMemsetAsync(ctl, 0, 4096, stream);                 // startup rendezvous

  void* kargs[] = {(void*)&Wg, (void*)&xpk, (void*)&hpkA, (void*)&hpkB,
                   (void*)&b_ih, (void*)&b_hh, (void*)&bar, (void*)&ctl};
  hipLaunchCooperativeKernel((const void*)k_gru_all, dim3(256), dim3(512),
                             kargs, 0, stream);

  // t=127 (odd) wrote hpkA
  k_fc1<<<dim3(128), dim3(256), 0, stream>>>(hpkA, fc1T, b_fc1, fc1o);
  k_fc2<<<dim3(128), dim3(256), 0, stream>>>(fc1o, w_fc2, b_fc2, out);
}